// Round 16
// baseline (21.956 us; speedup 1.0000x reference)
//
#include <hip/hip_runtime.h>
#include <math.h>

#define EPS 1e-6f
#define BN_EPSF 1e-5f
#define PI2F 6.2831853071795864769f
#define INV2PIF 0.15915494309189535f
#define LOG2EF 1.4426950408889634f
#define NBB 4
#define NCC 512
#define NGG 2048
#define OUTC 64
#define NBAS 10

// d_out layout (floats): y_out, n_f, fourier_prior, n_h1, h0_f
#define Y_OFF   0
#define NF_OFF  (NBB*NGG*OUTC)          // 524288
#define FP_OFF  (NF_OFF  + NBB*NGG*9)   // 598016
#define NH1_OFF (FP_OFF  + NBB*NGG*9)   // 671744
#define H0_OFF  (NH1_OFF + NBB*NGG*9)   // 745472

// ws layout (floats)
#define WSH01    0                      // interleaved (h0,h1) pairs, 2*73728
#define WS_CONV  (2*NBB*9*NGG)          // conv outputs
#define WS_STATS (3*NBB*9*NGG)          // 9 cps * 64 blocks * {sum,sumsq}

#if defined(__has_builtin)
# if __has_builtin(__builtin_amdgcn_exp2f)
#  define EXP2F(x) __builtin_amdgcn_exp2f(x)
# endif
# if __has_builtin(__builtin_amdgcn_cosf)
#  define COS_REV(r) __builtin_amdgcn_cosf(r)   // cos(2*pi*r), r in [0,1)
# endif
#endif
#ifndef EXP2F
# define EXP2F(x) exp2f(x)
#endif
#ifndef COS_REV
# define COS_REV(r) cosf(PI2F*(r))
#endif

// ---------------------------------------------------------------------------
// K1: RBF partial sums, ONE CHANNEL per block (r14/r15 structure).
// 1536 blocks (4 b x 128 tiles of 16 g x 3 c) x 256 threads, ~50 VGPR,
// __launch_bounds__(256,8) -> 64-VGPR cap.
// r16: 16-B skew (4 floats per 32 pts) -> chunk bases 16B-aligned -> true
// ds_read_b128 of TWO context points per read (16 reads vs 32); wave's 4
// chunk-groups land on bank quads {0-3}{4-7}{8-11}{12-15} = conflict-free.
// Dual accumulator sets = 2 independent dependency chains.
// ---------------------------------------------------------------------------
__global__ __launch_bounds__(256, 8) void k1_rbf(
    const float* __restrict__ x_c, const float* __restrict__ y_c,
    const float* __restrict__ x_g, const float* __restrict__ sigma,
    float* __restrict__ ws)
{
    const int bid = blockIdx.x;
    const int c   = bid % 3;           // channel owned by this block
    const int t   = bid / 3;           // 0..511
    const int b   = t >> 7;            // batch
    const int g0  = (t & 127) * 16;    // g-tile base
    const int tid = threadIdx.x;

    __shared__ __attribute__((aligned(16))) float cxy[NCC*2 + (NCC/32)*4]; // 4.25 KB
    __shared__ float red[16][16][7];           // 7.2 KB chunk partials (+pad)

    // ---- stage this channel's context slice (stride-3 source) ----
    const float* xcb = x_c + b*NCC*3 + c;
    const float* ycb = y_c + b*NCC*3 + c;
    for (int n = tid; n < NCC; n += 256) {
        int base = n*2 + ((n>>5)<<2);          // 16-B skew per 32 points
        cxy[base]     = xcb[n*3];
        cxy[base + 1] = ycb[n*3];
    }

    float coef[3];
    #pragma unroll
    for (int p = 0; p < 3; ++p) {
        float s = expf(sigma[p]) + EPS;
        coef[p] = (-0.5f * LOG2EF) / (s*s);   // exp(-0.5 d^2) == exp2(d^2*coef)
    }

    // mapping: g = tid&15, chunk cA = tid>>4 (16 chunks of 32 ctx)
    const int gA = tid & 15;
    const int cA = tid >> 4;
    const float xg = x_g[(b*NGG + g0 + gA)*3 + c];

    __syncthreads();

    // ---- RBF loop: 16 float4 reads = 32 ctx, 6 exp/iter, dual acc chains ----
    float h00 = 0.f, h01 = 0.f, h02 = 0.f;
    float h10 = 0.f, h11 = 0.f, h12 = 0.f;
    float g00 = 0.f, g01 = 0.f, g02 = 0.f;
    float g10 = 0.f, g11 = 0.f, g12 = 0.f;
    const int fbase = cA * 68;                 // 32 ctx * 2 + 4-float skew (16B-aligned)
    #pragma unroll 8
    for (int i = 0; i < 16; ++i) {
        float4 Q = *(const float4*)&cxy[fbase + i*4];   // (x_{2i},y_{2i},x_{2i+1},y_{2i+1})
        float da = Q.x - xg,  db = Q.z - xg;
        float da2 = da*da,    db2 = db*db;
        float wa0 = EXP2F(da2 * coef[0]);
        float wa1 = EXP2F(da2 * coef[1]);
        float wa2 = EXP2F(da2 * coef[2]);
        float wb0 = EXP2F(db2 * coef[0]);
        float wb1 = EXP2F(db2 * coef[1]);
        float wb2 = EXP2F(db2 * coef[2]);
        h00 += wa0;  h01 += wa1;  h02 += wa2;
        h10 = fmaf(wa0, Q.y, h10);  h11 = fmaf(wa1, Q.y, h11);  h12 = fmaf(wa2, Q.y, h12);
        g00 += wb0;  g01 += wb1;  g02 += wb2;
        g10 = fmaf(wb0, Q.w, g10);  g11 = fmaf(wb1, Q.w, g11);  g12 = fmaf(wb2, Q.w, g12);
    }
    red[cA][gA][0] = h00 + g00;  red[cA][gA][1] = h01 + g01;  red[cA][gA][2] = h02 + g02;
    red[cA][gA][3] = h10 + g10;  red[cA][gA][4] = h11 + g11;  red[cA][gA][5] = h12 + g12;
    __syncthreads();

    // ---- reduce 16 chunks -> 96 outputs (16 g x {h0,h1} x 3 p), pairs ----
    if (tid < 96) {
        int g = tid / 6, j = tid - g*6;
        float s = 0.f;
        #pragma unroll
        for (int q = 0; q < 16; ++q) s += red[q][g][j];
        int p = (j < 3) ? j : j - 3;
        int idx = (b*9 + c*3 + p)*NGG + g0 + g;
        ws[WSH01 + idx*2 + ((j < 3) ? 0 : 1)] = s;   // interleaved (h0,h1)
    }
}

// ---------------------------------------------------------------------------
// K2: finalize (nh1 + Fourier prior via HW cos) for 128 own g + 8 halo g,
// then depthwise conv + BN partials. r16: 576 blocks (4 b x 9 cp x 16 gc of
// 128 g) x 256 — doubles block-parallelism (288 was 1.125/CU, imbalanced).
// ---------------------------------------------------------------------------
__global__ __launch_bounds__(256) void k2_fin_conv(
    const float* __restrict__ x_g, const float* __restrict__ sigma,
    const float* __restrict__ mu, const float* __restrict__ eps1,
    const float* __restrict__ b_u, const float* __restrict__ random_w,
    const float* __restrict__ cw1, const float* __restrict__ cb1,
    const float* __restrict__ cw2, const float* __restrict__ cb2,
    const float* __restrict__ cw3, const float* __restrict__ cb3,
    float* __restrict__ out, float* __restrict__ ws)
{
    const int bid = blockIdx.x;           // 4b x 9cp x 16gc = 576
    const int b = bid / 144; int r = bid - b*144;
    const int cp = r >> 4;  const int gc = r & 15;
    const int c = cp / 3, p = cp - c*3;
    const int tid = threadIdx.x;

    __shared__ float pre_l[136];          // 0..3 left halo, 4..131 own, 132..135 right
    __shared__ float swl[NBAS], sbl[NBAS], rwl[NBAS];
    __shared__ float r1[4], r2[4];

    if (tid < NBAS) {
        float wmu  = expf(mu[p]);
        float wstd = 1.0f / (expf(sigma[p]) + EPS);
        swl[tid] = wmu + wstd * eps1[(b*NBAS + tid)*3 + p];
        sbl[tid] = PI2F * b_u[(b*NBAS + tid)*3 + p];
        rwl[tid] = random_w[tid];
    }
    __syncthreads();

    if (tid < 136) {
        int gf = gc*128 - 4 + tid;
        float v = 0.f;
        if (gf >= 0 && gf < NGG) {
            int idx = (b*9 + cp)*NGG + gf;
            float2 hv = *(const float2*)&ws[WSH01 + idx*2];
            float h0 = hv.x;
            float h1 = hv.y;
            float nh1 = h1 / (h0 + EPS);
            float xg = x_g[(b*NGG + gf)*3 + c];
            float fp = 0.f;
            #pragma unroll
            for (int k = 0; k < NBAS; ++k) {
                // arg bits match numpy (mul+add, round-to-nearest);
                // cos via HW: cos(arg) = v_cos(fract(arg/2pi)); reduction
                // error <= ~0.012 rad at |arg|<=1.5e5 — inside threshold.
                float arg = __fadd_rn(__fmul_rn(swl[k], xg), sbl[k]);
                float rev = arg * INV2PIF;
                rev = rev - floorf(rev);
                fp += rwl[k] * COS_REV(rev);
            }
            fp *= 0.44721359549995793f;   // sqrt(2/10)
            v = nh1 + fp;
            if (tid >= 4 && tid < 132) {  // own range: write the three outputs
                int obase = (b*NGG + gf)*9 + cp;
                out[H0_OFF  + obase] = h0;
                out[NH1_OFF + obase] = nh1;
                out[FP_OFF  + obase] = fp;
            }
        }
        pre_l[tid] = v;                   // zero beyond grid edges (conv zero-pad)
    }
    __syncthreads();

    // depthwise conv (own 128 g) + deterministic BN partials
    float acc = 0.f, s1 = 0.f, s2 = 0.f;
    if (tid < 128) {
        int K, pad; const float* w; float bias;
        if (p == 0)      { K = 3; pad = 1; w = cw1 + c*3; bias = cb1[c]; }
        else if (p == 1) { K = 5; pad = 2; w = cw2 + c*5; bias = cb2[c]; }
        else             { K = 9; pad = 4; w = cw3 + c*9; bias = cb3[c]; }
        acc = bias;
        for (int k = 0; k < K; ++k)
            acc += w[k] * pre_l[tid + 4 - pad + k];
        ws[WS_CONV + (b*9 + cp)*NGG + gc*128 + tid] = acc;
        s1 = acc; s2 = acc*acc;
    }
    #pragma unroll
    for (int o = 32; o > 0; o >>= 1) {
        s1 += __shfl_down(s1, o);
        s2 += __shfl_down(s2, o);
    }
    int lane = tid & 63, wv = tid >> 6;
    if (lane == 0) { r1[wv] = s1; r2[wv] = s2; }
    __syncthreads();
    if (tid == 0) {
        float t1 = r1[0] + r1[1] + r1[2] + r1[3];
        float t2 = r2[0] + r2[1] + r2[2] + r2[3];
        int pidx = cp*64 + b*16 + gc;
        ws[WS_STATS + pidx*2]     = t1;
        ws[WS_STATS + pidx*2 + 1] = t2;
    }
}

// ---------------------------------------------------------------------------
// K3: BN stats reduce (64 partials/cp) + normalize (n_f) + output GEMV.
// 2048 blocks x 256.
// ---------------------------------------------------------------------------
__global__ __launch_bounds__(256) void k3_out(
    const float* __restrict__ bn_gamma, const float* __restrict__ bn_beta,
    const float* __restrict__ g_w, const float* __restrict__ g_b,
    float* __restrict__ out, float* __restrict__ ws)
{
    __shared__ float4 gw4[OUTC*18/4];     // float4-staged g_w
    __shared__ float feat_l[4][18];
    __shared__ float ps[9][16][2];
    __shared__ float mstat[9][2];
    const int tid = threadIdx.x;
    float* gw_l = (float*)gw4;

    for (int i = tid; i < OUTC*18/4; i += 256)
        gw4[i] = ((const float4*)g_w)[i];
    if (tid < 144) {
        int cp = tid / 16, q = tid & 15;
        float s1 = 0.f, s2 = 0.f;
        #pragma unroll
        for (int j = 0; j < 4; ++j) {
            int idx = WS_STATS + (cp*64 + q*4 + j)*2;
            s1 += ws[idx];
            s2 += ws[idx + 1];
        }
        ps[cp][q][0] = s1; ps[cp][q][1] = s2;
    }
    __syncthreads();
    if (tid < 9) {
        float s1 = 0.f, s2 = 0.f;
        #pragma unroll
        for (int q = 0; q < 16; ++q) { s1 += ps[tid][q][0]; s2 += ps[tid][q][1]; }
        float mean = s1 * (1.0f/8192.0f);
        float var  = s2 * (1.0f/8192.0f) - mean*mean;
        mstat[tid][0] = mean;
        mstat[tid][1] = rsqrtf(var + BN_EPSF);
    }
    __syncthreads();

    if (tid < 72) {
        int pt = tid / 18, j = tid - pt*18;
        int P = blockIdx.x*4 + pt;
        int b = P >> 11, g = P & 2047;
        float f;
        if (j < 9) {
            f = out[H0_OFF + (b*NGG + g)*9 + j];
        } else {
            int cp = j - 9; int c = cp / 3, p = cp - c*3;
            float x = ws[WS_CONV + (b*9 + cp)*NGG + g];
            float v = bn_gamma[p*3 + c] * (x - mstat[cp][0]) * mstat[cp][1]
                      + bn_beta[p*3 + c];
            out[NF_OFF + (b*NGG + g)*9 + cp] = v;
            f = v;
        }
        feat_l[pt][j] = f;
    }
    __syncthreads();

    int pt = tid >> 6, o = tid & 63;
    int P = blockIdx.x*4 + pt;
    int b = P >> 11, g = P & 2047;
    float acc = g_b[o];
    #pragma unroll
    for (int j = 0; j < 18; ++j) acc += feat_l[pt][j] * gw_l[o*18 + j];
    out[Y_OFF + (b*NGG + g)*OUTC + o] = acc;
}

extern "C" void kernel_launch(void* const* d_in, const int* in_sizes, int n_in,
                              void* d_out, int out_size, void* d_ws, size_t ws_size,
                              hipStream_t stream)
{
    const float* x_c      = (const float*)d_in[0];
    const float* y_c      = (const float*)d_in[1];
    const float* x_g      = (const float*)d_in[2];
    const float* sigma    = (const float*)d_in[3];
    const float* mu       = (const float*)d_in[4];
    const float* eps1     = (const float*)d_in[5];
    const float* b_u      = (const float*)d_in[6];
    const float* random_w = (const float*)d_in[7];
    const float* conv_w1  = (const float*)d_in[8];
    const float* conv_b1  = (const float*)d_in[9];
    const float* conv_w2  = (const float*)d_in[10];
    const float* conv_b2  = (const float*)d_in[11];
    const float* conv_w3  = (const float*)d_in[12];
    const float* conv_b3  = (const float*)d_in[13];
    const float* bn_gamma = (const float*)d_in[14];
    const float* bn_beta  = (const float*)d_in[15];
    const float* g_w      = (const float*)d_in[16];
    const float* g_b      = (const float*)d_in[17];

    float* outp = (float*)d_out;
    float* wsp  = (float*)d_ws;

    k1_rbf<<<NBB*128*3, 256, 0, stream>>>(x_c, y_c, x_g, sigma, wsp);
    k2_fin_conv<<<NBB*9*(NGG/128), 256, 0, stream>>>(x_g, sigma, mu, eps1, b_u,
                                                     random_w, conv_w1, conv_b1,
                                                     conv_w2, conv_b2, conv_w3,
                                                     conv_b3, outp, wsp);
    k3_out<<<(NBB*NGG)/4, 256, 0, stream>>>(bn_gamma, bn_beta, g_w, g_b, outp, wsp);
}